// Round 7
// baseline (235.697 us; speedup 1.0000x reference)
//
#include <hip/hip_runtime.h>
#include <hip/hip_bf16.h>

// Problem constants
#define FIN 250
#define NROWS 129024              // 2048*63 nodes
#define NTILES 4032               // NROWS / 32
#define NBLOCKS 512

typedef short short8 __attribute__((ext_vector_type(8)));
typedef float f32x4 __attribute__((ext_vector_type(4)));

__device__ __forceinline__ short f2bf(float f) {
    __bf16 b = (__bf16)f;           // RNE convert
    return __builtin_bit_cast(short, b);
}

#define GS(p, v, off) \
    asm volatile("global_store_dword %0, %1, off offset:" #off :: "v"(p), "v"(v) : "memory")
#define WAITV(n) asm volatile("s_waitcnt vmcnt(" #n ")" ::: "memory")
#define SCHEDF __builtin_amdgcn_sched_barrier(0)
#define HWBAR do { asm volatile("" ::: "memory"); __builtin_amdgcn_s_barrier(); \
                   asm volatile("" ::: "memory"); } while (0)

// Stage one 32-row x-tile (row pitch 1024B in LDS) via global_load_lds width-16.
// XOR-swizzle ((r&7)<<4) applied on the GLOBAL per-lane address (LDS dest stays linear);
// the read side applies the same XOR. Wave wv stages rows wv*4 .. wv*4+3 (4 instrs = 4 vmcnt).
__device__ __forceinline__ void stage_tile(const float* __restrict__ x,
                                           const float* __restrict__ xlast,
                                           char* lbuf, int tile, int wv, int lane) {
    #pragma unroll
    for (int i = 0; i < 4; ++i) {
        int r = wv * 4 + i;
        long grow = (long)tile * 32 + r;
        int s = r & 7;
        const char* g;
        if (grow == (long)NROWS - 1) g = (const char*)xlast;        // padded copy (OOB-safe)
        else                         g = (const char*)x + grow * 1000L;
        g += ((lane ^ s) << 4);
        char* l = lbuf + r * 1024;                                   // wave-uniform dest base
        __builtin_amdgcn_global_load_lds(
            (const __attribute__((address_space(1))) void*)g,
            (__attribute__((address_space(3))) void*)l, 16, 0, 0);
    }
}

// Compute one tile: 8 kk x {2 row-frags x 2 col-frags} MFMAs. B-frags in registers.
__device__ __forceinline__ void compute_tile(const char* buf, const short8 (&b)[2][8],
                                             f32x4 (&acc)[2][2], int m, int kg) {
    const int swz = (m & 7) << 4;
    const char* row0 = buf + m * 1024;
    const char* row1 = buf + (16 + m) * 1024;
    #pragma unroll
    for (int kk = 0; kk < 8; ++kk) {
        int base = kk * 128 + kg * 32;
        float4 u0 = *(const float4*)(row0 + ((base) ^ swz));
        float4 u1 = *(const float4*)(row0 + ((base + 16) ^ swz));
        float4 w0 = *(const float4*)(row1 + ((base) ^ swz));
        float4 w1 = *(const float4*)(row1 + ((base + 16) ^ swz));
        short8 a0, a1;
        a0[0] = f2bf(u0.x); a0[1] = f2bf(u0.y); a0[2] = f2bf(u0.z); a0[3] = f2bf(u0.w);
        a0[4] = f2bf(u1.x); a0[5] = f2bf(u1.y); a0[6] = f2bf(u1.z); a0[7] = f2bf(u1.w);
        a1[0] = f2bf(w0.x); a1[1] = f2bf(w0.y); a1[2] = f2bf(w0.z); a1[3] = f2bf(w0.w);
        a1[4] = f2bf(w1.x); a1[5] = f2bf(w1.y); a1[6] = f2bf(w1.z); a1[7] = f2bf(w1.w);
        acc[0][0] = __builtin_amdgcn_mfma_f32_16x16x32_bf16(a0, b[0][kk], acc[0][0], 0, 0, 0);
        acc[0][1] = __builtin_amdgcn_mfma_f32_16x16x32_bf16(a0, b[1][kk], acc[0][1], 0, 0, 0);
        acc[1][0] = __builtin_amdgcn_mfma_f32_16x16x32_bf16(a1, b[0][kk], acc[1][0], 0, 0, 0);
        acc[1][1] = __builtin_amdgcn_mfma_f32_16x16x32_bf16(a1, b[1][kk], acc[1][1], 0, 0, 0);
    }
}

// 16 inline-asm stores per wave per tile (fixed vmcnt count on all paths).
__device__ __forceinline__ void store_tile(float* __restrict__ out, int tile, int wv,
                                           int m, int kg, const f32x4 (&acc)[2][2]) {
    float* p0 = out + ((size_t)tile * 32 + (size_t)kg * 4) * FIN + wv * 32 + m;
    float* p1 = p0 + 16 * FIN;
    if (wv < 7) {
        GS(p0, acc[0][0][0], 0);    GS(p0, acc[0][0][1], 1000);
        GS(p0, acc[0][0][2], 2000); GS(p0, acc[0][0][3], 3000);
        GS(p0, acc[0][1][0], 64);   GS(p0, acc[0][1][1], 1064);
        GS(p0, acc[0][1][2], 2064); GS(p0, acc[0][1][3], 3064);
        GS(p1, acc[1][0][0], 0);    GS(p1, acc[1][0][1], 1000);
        GS(p1, acc[1][0][2], 2000); GS(p1, acc[1][0][3], 3000);
        GS(p1, acc[1][1][0], 64);   GS(p1, acc[1][1][1], 1064);
        GS(p1, acc[1][1][2], 2064); GS(p1, acc[1][1][3], 3064);
    } else {
        GS(p0, acc[0][0][0], 0);    GS(p0, acc[0][0][1], 1000);
        GS(p0, acc[0][0][2], 2000); GS(p0, acc[0][0][3], 3000);
        GS(p1, acc[1][0][0], 0);    GS(p1, acc[1][0][1], 1000);
        GS(p1, acc[1][0][2], 2000); GS(p1, acc[1][0][3], 3000);
        if (m < 10) {   // cols 240..249 only
            GS(p0, acc[0][1][0], 64);   GS(p0, acc[0][1][1], 1064);
            GS(p0, acc[0][1][2], 2064); GS(p0, acc[0][1][3], 3064);
            GS(p1, acc[1][1][0], 64);   GS(p1, acc[1][1][1], 1064);
            GS(p1, acc[1][1][2], 2064); GS(p1, acc[1][1][3], 3064);
        }
    }
}

// Pre-kernel: W^T bf16 image [c(256)][k(256 padded, k-pairs packed)] + padded last-x-row copy.
__global__ void __launch_bounds__(256)
wt_prep(const float* __restrict__ W, const float* __restrict__ x,
        unsigned* __restrict__ Wt, float* __restrict__ xlast) {
    int i = blockIdx.x * 256 + threadIdx.x;       // 128 blocks x 256 = 32768 words
    unsigned c  = (unsigned)i & 255u;
    unsigned kp = (unsigned)i >> 8;               // 0..127
    unsigned k0 = 2u * kp;
    unsigned lo = 0u, hi = 0u;
    if (c < FIN) {
        if (k0 < FIN)      lo = (unsigned)(unsigned short)f2bf(W[k0 * FIN + c]);
        if (k0 + 1u < FIN) hi = (unsigned)(unsigned short)f2bf(W[(k0 + 1u) * FIN + c]);
    }
    Wt[(c << 7) + kp] = lo | (hi << 16);
    if (blockIdx.x == 0) {
        int t = threadIdx.x;                      // 256 floats = 1024 B padded row
        xlast[t] = (t < FIN) ? x[(size_t)(NROWS - 1) * FIN + t] : 0.f;
    }
}

#define ACCINIT do { \
    acc[0][0] = (f32x4){bc0, bc0, bc0, bc0}; acc[0][1] = (f32x4){bc1, bc1, bc1, bc1}; \
    acc[1][0] = (f32x4){bc0, bc0, bc0, bc0}; acc[1][1] = (f32x4){bc1, bc1, bc1, bc1}; \
} while (0)

__global__ void __launch_bounds__(512, 4) __attribute__((amdgpu_num_vgpr(128)))
gat_gemm(const float* __restrict__ x, const unsigned short* __restrict__ Wt,
         const float* __restrict__ xlast, const float* __restrict__ bias,
         const float* __restrict__ att_src, const float* __restrict__ att_dst,
         unsigned* __restrict__ cnt, float* __restrict__ out)
{
    __shared__ __align__(16) char lds[65536];     // 2 x 32768B tile buffers
    __shared__ float asrc[64], adst[64];
    __shared__ unsigned lastFlag;

    const int tid  = threadIdx.x;
    const int lane = tid & 63;
    const int wv   = tid >> 6;        // 0..7, owns cols wv*32 .. wv*32+31
    const int m    = lane & 15;
    const int kg   = lane >> 4;
    const int cb   = wv * 32;

    // ---- B-fragments in registers for the whole kernel (64 VGPRs) ----
    short8 b[2][8];
    const char* wb = (const char*)Wt;
    #pragma unroll
    for (int nf = 0; nf < 2; ++nf)
        #pragma unroll
        for (int kk = 0; kk < 8; ++kk)
            b[nf][kk] = *(const short8*)(wb + ((size_t)(cb + nf * 16 + m) << 9) + kk * 64 + kg * 16);

    float bc0 = (cb + m      < FIN) ? bias[cb + m]      : 0.f;
    float bc1 = (cb + 16 + m < FIN) ? bias[cb + 16 + m] : 0.f;

    WAITV(0); SCHEDF;                 // clean vmcnt slate before counted pipeline

    const int bid = blockIdx.x;
    const int nt  = (NTILES - bid + NBLOCKS - 1) / NBLOCKS;   // 7 or 8, >=2

    stage_tile(x, xlast, lds,         bid,           wv, lane);
    stage_tile(x, xlast, lds + 32768, bid + NBLOCKS, wv, lane);

    f32x4 acc[2][2];

    // ---- first tile: wait own 4 stage ops of buf0 (buf1's 4 stay in flight) ----
    WAITV(4); SCHEDF; HWBAR; SCHEDF;
    ACCINIT;
    compute_tile(lds, b, acc, m, kg);
    SCHEDF; HWBAR; SCHEDF;
    store_tile(out, bid, wv, m, kg, acc);

    for (int i = 1; i < nt - 1; ++i) {
        int t = bid + i * NBLOCKS;
        stage_tile(x, xlast, lds + (((i + 1) & 1) ? 32768 : 0), t + NBLOCKS, wv, lane);
        // newer ops: 16 stores(prev) + 4 stages(next) = 20 -> current tile's stages drained
        WAITV(20); SCHEDF; HWBAR; SCHEDF;
        ACCINIT;
        compute_tile(lds + ((i & 1) ? 32768 : 0), b, acc, m, kg);
        SCHEDF; HWBAR; SCHEDF;
        store_tile(out, t, wv, m, kg, acc);
    }
    {   // last tile: newer ops = 16 stores(prev) only
        int t = bid + (nt - 1) * NBLOCKS;
        WAITV(16); SCHEDF; HWBAR; SCHEDF;
        ACCINIT;
        compute_tile(lds + (((nt - 1) & 1) ? 32768 : 0), b, acc, m, kg);
        SCHEDF; HWBAR; SCHEDF;
        store_tile(out, t, wv, m, kg, acc);
    }

    // ---- fused attention tail (rows 0..62 hold h; bias=0 here) ----
    WAITV(0);
    __syncthreads();
    if (tid == 0) {
        __threadfence();
        lastFlag = (atomicAdd(cnt, 1u) == NBLOCKS - 1) ? 1u : 0u;
    }
    __syncthreads();
    if (!lastFlag) return;
    __threadfence();

    float* al = (float*)lds;          // alpha 63x64 f32 (buffers dead)

    {   // logits: 32 groups of 16 threads, shfl-reduce over global h rows
        int g = tid >> 4, t = tid & 15;
        for (int r = g; r < 63; r += 32) {
            float s1 = 0.f, s2 = 0.f;
            for (int k = t; k < FIN; k += 16) {
                float h = out[r * FIN + k];
                s1 += h * att_src[k];
                s2 += h * att_dst[k];
            }
            #pragma unroll
            for (int o = 8; o >= 1; o >>= 1) {
                s1 += __shfl_xor(s1, o, 16);
                s2 += __shfl_xor(s2, o, 16);
            }
            if (t == 0) { asrc[r] = s1; adst[r] = s2; }
        }
    }
    __syncthreads();

    {   // softmax per dst row -> al
        int g = tid >> 4, t = tid & 15;
        for (int d = g; d < 63; d += 32) {
            float ad = adst[d];
            float e_[4];
            float mx = -1e30f;
            #pragma unroll
            for (int q = 0; q < 4; ++q) {
                int sdx = t + q * 16;
                float e = -1e30f;
                if (sdx < 63) {
                    e = asrc[sdx] + ad;
                    e = e > 0.f ? e : 0.2f * e;     // leaky_relu slope 0.2
                }
                e_[q] = e;
                mx = fmaxf(mx, e);
            }
            #pragma unroll
            for (int o = 8; o >= 1; o >>= 1) mx = fmaxf(mx, __shfl_xor(mx, o, 16));
            float den = 0.f;
            #pragma unroll
            for (int q = 0; q < 4; ++q) {
                int sdx = t + q * 16;
                float ex = (sdx < 63) ? __expf(e_[q] - mx) : 0.f;
                e_[q] = ex;
                den += ex;
            }
            #pragma unroll
            for (int o = 8; o >= 1; o >>= 1) den += __shfl_xor(den, o, 16);
            float rd = 1.f / den;
            #pragma unroll
            for (int q = 0; q < 4; ++q) {
                int sdx = t + q * 16;
                if (sdx < 63) al[d * 64 + sdx] = e_[q] * rd;
            }
        }
    }
    __syncthreads();

    {   // mix: accumulate into registers (reads), sync, then overwrite rows 0..62
        int d = tid >> 3, ts = tid & 7;
        int fb = ts * 32;
        float v[32];
        if (d < 63) {
            #pragma unroll
            for (int j = 0; j < 32; ++j) v[j] = 0.f;
            for (int s = 0; s < 63; ++s) {
                float a = al[d * 64 + s];
                const float* hp = out + s * FIN + fb;
                #pragma unroll
                for (int j = 0; j < 32; ++j) v[j] += a * hp[j];
            }
        }
        __syncthreads();
        if (d < 63) {
            float* op = out + d * FIN + fb;
            #pragma unroll
            for (int j = 0; j < 32; ++j)
                if (fb + j < FIN) op[j] = v[j];
        }
    }
}

extern "C" void kernel_launch(void* const* d_in, const int* in_sizes, int n_in,
                              void* d_out, int out_size, void* d_ws, size_t ws_size,
                              hipStream_t stream) {
    (void)in_sizes; (void)n_in; (void)ws_size; (void)out_size;
    const float* x        = (const float*)d_in[0];
    const float* W        = (const float*)d_in[1];
    const float* att_src  = (const float*)d_in[2];
    const float* att_dst  = (const float*)d_in[3];
    const float* bias     = (const float*)d_in[4];
    float* out            = (float*)d_out;
    unsigned* cnt         = (unsigned*)d_ws;                         // 4 B
    unsigned* Wt          = (unsigned*)((char*)d_ws + 256);          // 128 KiB image
    float* xlast          = (float*)((char*)d_ws + 256 + 131072);    // 1 KiB padded row

    hipMemsetAsync(cnt, 0, 4, stream);
    wt_prep<<<128, 256, 0, stream>>>(W, x, Wt, xlast);
    gat_gemm<<<NBLOCKS, 512, 0, stream>>>(x, (const unsigned short*)Wt, xlast,
                                          bias, att_src, att_dst, cnt, out);
}

// Round 8
// 208.418 us; speedup vs baseline: 1.1309x; 1.1309x over previous
//
#include <hip/hip_runtime.h>
#include <hip/hip_bf16.h>

// Problem constants (fixed by setup_inputs)
#define FIN 250
#define NROWS 129024              // 2048*63 nodes
#define NSTRIPES (NROWS / 16)     // 8064 stripes of 16 rows
#define TOTXF (NROWS * FIN)       // 32256000 floats in x
#define NBLOCKS 256
#define WAVES_PER_BLOCK 12
#define NWAVES_TOT (NBLOCKS * WAVES_PER_BLOCK)   // 3072

typedef short short8 __attribute__((ext_vector_type(8)));
typedef float f32x4 __attribute__((ext_vector_type(4)));

__device__ __forceinline__ short f2bf(float f) {
    __bf16 b = (__bf16)f;           // RNE convert
    return __builtin_bit_cast(short, b);
}

// 32 float2 loads for one stripe's A slice (lane layout: row=m, k=kg*8 + kk*32 + 0..7).
// Plain C++ loads; single base + small imm offsets. (R1-proven: compiler keeps buf live
// at min_waves=1 and pipelines the vmcnt waits into the next compute.)
__device__ __forceinline__ void load_stripe_fast(float2 (&buf)[32], const float* __restrict__ x,
                                                 int stripe, int m, int kg) {
    const float* base = x + (unsigned)(stripe * 16 + m) * FIN + (unsigned)(kg * 8);
    #pragma unroll
    for (int kk = 0; kk < 8; ++kk) {
        #pragma unroll
        for (int p = 0; p < 4; ++p) {
            buf[kk * 4 + p] = *(const float2*)(base + kk * 32 + p * 2);
        }
    }
}

// Safe path (last stripe only): clamp in-bounds; k>=250 overreach hits zeroed W rows.
__device__ __forceinline__ void load_stripe_safe(float2 (&buf)[32], const float* __restrict__ x,
                                                 int stripe, int m, int kg) {
    unsigned fbase = (unsigned)(stripe * 16 + m) * FIN + (unsigned)(kg * 8);
    #pragma unroll
    for (int kk = 0; kk < 8; ++kk) {
        #pragma unroll
        for (int p = 0; p < 4; ++p) {
            unsigned idx = fbase + (unsigned)(kk * 32 + p * 2);
            idx = idx > (TOTXF - 2u) ? (TOTXF - 2u) : idx;
            buf[kk * 4 + p] = *(const float2*)(x + idx);
        }
    }
}

// MFMA + store for one col-half (8 nf frags) of a stripe.
__device__ __forceinline__ void mfma_half(const short8 (&af)[8],
                                          const unsigned short* wt,
                                          float* __restrict__ out,
                                          int stripe, int half, int m, int kg,
                                          unsigned bswz, const float (&bcol)[16]) {
    f32x4 acc[8];
    #pragma unroll
    for (int nf = 0; nf < 8; ++nf) {
        float b = bcol[half * 8 + nf];
        acc[nf] = (f32x4){b, b, b, b};       // bias baked into accumulator init
    }

    const unsigned chbase = (unsigned)(half * 128) * 512u;
    #pragma unroll
    for (int kk = 0; kk < 8; ++kk) {
        #pragma unroll
        for (int nf = 0; nf < 8; ++nf) {
            unsigned off = chbase + (unsigned)(nf * 16 + m) * 512u
                         + (((unsigned)(kk * 64 + kg * 16)) ^ bswz);
            short8 bf = *(const short8*)((const char*)wt + off);
            acc[nf] = __builtin_amdgcn_mfma_f32_16x16x32_bf16(af[kk], bf, acc[nf], 0, 0, 0);
        }
    }
    // C/D layout: col=lane&15(=m), row=(lane>>4)*4+j
    unsigned obase = (unsigned)(stripe * 16 + kg * 4) * FIN + (unsigned)(half * 128 + m);
    #pragma unroll
    for (int nf = 0; nf < 8; ++nf) {
        if (half == 0 || nf < 7 || m < 10) {   // mask cols 250..255
            #pragma unroll
            for (int j = 0; j < 4; ++j) {
                out[obase + (unsigned)(j * FIN) + (unsigned)(nf * 16)] = acc[nf][j];
            }
        }
    }
}

// Convert one stripe's fp32 buffer to bf16 A-fragments, then run both col-halves.
__device__ __forceinline__ void compute_stripe(const float2 (&buf)[32], short8 (&af)[8],
                                               const unsigned short* wt,
                                               float* __restrict__ out,
                                               int stripe, int m, int kg,
                                               unsigned bswz, const float (&bcol)[16]) {
    #pragma unroll
    for (int kk = 0; kk < 8; ++kk) {
        #pragma unroll
        for (int p = 0; p < 4; ++p) {
            af[kk][2 * p]     = f2bf(buf[kk * 4 + p].x);
            af[kk][2 * p + 1] = f2bf(buf[kk * 4 + p].y);
        }
    }
    mfma_half(af, wt, out, stripe, 0, m, kg, bswz, bcol);
    mfma_half(af, wt, out, stripe, 1, m, kg, bswz, bcol);
}

// Pre-kernel: build the exact 128-KiB LDS image of W^T (bf16, [c(256)][k(256)],
// 512 B/row, k-pairs packed, XOR-swizzled, zero-padded) into global scratch.
__global__ void __launch_bounds__(256)
wt_prep(const float* __restrict__ W, unsigned* __restrict__ Wt) {
    int i = blockIdx.x * 256 + threadIdx.x;   // 128 blocks x 256 thr = 32768 words
    unsigned c  = (unsigned)i & 255u;
    unsigned kp = (unsigned)i >> 8;           // 0..127
    unsigned k0 = 2u * kp;
    unsigned lo = 0u, hi = 0u;
    if (c < FIN) {
        if (k0 < FIN)      lo = (unsigned)(unsigned short)f2bf(W[k0 * FIN + c]);
        if (k0 + 1u < FIN) hi = (unsigned)(unsigned short)f2bf(W[(k0 + 1u) * FIN + c]);
    }
    unsigned off = (c << 9) + ((4u * kp) ^ ((c & 7u) << 4));
    *(unsigned*)((char*)Wt + off) = lo | (hi << 16);
}

// min_waves=1: R1-proven to let the allocator keep the 64-reg dbuf live (VGPR~164).
__global__ void __launch_bounds__(768, 1)
gat_gemm(const float* __restrict__ x, const unsigned* __restrict__ Wt,
         const float* __restrict__ bias,
         const float* __restrict__ att_src, const float* __restrict__ att_dst,
         unsigned* __restrict__ cnt, float* __restrict__ out)
{
    __shared__ __align__(16) unsigned short wt[256 * 256];   // 128 KiB W^T image
    __shared__ float asrc[64], adst[64];
    __shared__ unsigned lastFlag;

    const int tid = threadIdx.x;

    // Stage pre-built image: dumb vector copy (L2/L3-served after first blocks)
    {
        const uint4* s4 = (const uint4*)Wt;
        uint4* d4 = (uint4*)wt;
        for (int i = tid; i < 8192; i += 768) d4[i] = s4[i];
    }
    __syncthreads();

    const int lane = tid & 63;
    const int m    = lane & 15;
    const int kg   = lane >> 4;
    const unsigned bswz = ((unsigned)(m & 7)) << 4;
    const int wv   = tid >> 6;                         // 0..11
    // Transposed mapping: wave w of block b -> w*256+b, so the 3-vs-2-stripe
    // imbalance spreads across all blocks (~31-32 stripes per block).
    const int gwT  = wv * NBLOCKS + blockIdx.x;        // 0..3071

    float bcol[16];
    #pragma unroll
    for (int nf = 0; nf < 16; ++nf) {
        int c = nf * 16 + m;
        bcol[nf] = (c < FIN) ? bias[c] : 0.f;
    }

    // R1-style register ping-pong double buffer across stripes.
    float2 bufA[32], bufB[32];
    short8 af[8];

    int s = gwT;
    if (s < NSTRIPES - 1) load_stripe_fast(bufA, x, s, m, kg);
    else                  load_stripe_safe(bufA, x, s, m, kg);

    for (;;) {
        int sB = s + NWAVES_TOT;
        if (sB < NSTRIPES - 1)       load_stripe_fast(bufB, x, sB, m, kg);
        else if (sB == NSTRIPES - 1) load_stripe_safe(bufB, x, sB, m, kg);

        compute_stripe(bufA, af, wt, out, s, m, kg, bswz, bcol);
        if (sB >= NSTRIPES) break;

        int sA = sB + NWAVES_TOT;
        if (sA < NSTRIPES - 1)       load_stripe_fast(bufA, x, sA, m, kg);
        else if (sA == NSTRIPES - 1) load_stripe_safe(bufA, x, sA, m, kg);

        compute_stripe(bufB, af, wt, out, sB, m, kg, bswz, bcol);
        if (sA >= NSTRIPES) break;
        s = sA;
    }

    // ---- last-block attention tail (rows 0..62 of out hold h+bias) ----
    // Exact: uniform logit shifts cancel in softmax; sum(alpha)=1 folds bias in.
    __syncthreads();
    if (tid == 0) {
        __threadfence();                               // release our out-writes
        unsigned old = atomicAdd(cnt, 1u);             // device-scope
        lastFlag = (old == NBLOCKS - 1) ? 1u : 0u;
    }
    __syncthreads();
    if (lastFlag == 0u) return;
    __threadfence();                                   // acquire others' out-writes

    float* hs    = (float*)wt;                         // 63x252 f32
    float* alpha = (float*)((char*)wt + 65536);        // 63x64 f32

    for (int idx = tid; idx < 63 * FIN; idx += 768) {
        int r = idx / FIN, f = idx - r * FIN;
        hs[r * 252 + f] = out[idx];
    }
    __syncthreads();

    {   // logits: 16 threads per row, shfl-reduce
        int g = tid >> 4, t = tid & 15;
        for (int r = g; r < 63; r += 48) {
            float s1 = 0.f, s2 = 0.f;
            for (int k = t; k < FIN; k += 16) {
                float h = hs[r * 252 + k];
                s1 += h * att_src[k];
                s2 += h * att_dst[k];
            }
            #pragma unroll
            for (int o = 8; o >= 1; o >>= 1) {
                s1 += __shfl_xor(s1, o, 16);
                s2 += __shfl_xor(s2, o, 16);
            }
            if (t == 0) { asrc[r] = s1; adst[r] = s2; }
        }
    }
    __syncthreads();

    {   // softmax per dst row: 16 threads per row
        int g = tid >> 4, t = tid & 15;
        for (int d = g; d < 63; d += 48) {
            float ad = adst[d];
            float e_[4];
            float mx = -1e30f;
            #pragma unroll
            for (int q = 0; q < 4; ++q) {
                int sdx = t + q * 16;
                float e = -1e30f;
                if (sdx < 63) {
                    e = asrc[sdx] + ad;
                    e = e > 0.f ? e : 0.2f * e;     // leaky_relu slope 0.2
                }
                e_[q] = e;
                mx = fmaxf(mx, e);
            }
            #pragma unroll
            for (int o = 8; o >= 1; o >>= 1) mx = fmaxf(mx, __shfl_xor(mx, o, 16));
            float den = 0.f;
            #pragma unroll
            for (int q = 0; q < 4; ++q) {
                int sdx = t + q * 16;
                float ex = (sdx < 63) ? __expf(e_[q] - mx) : 0.f;
                e_[q] = ex;
                den += ex;
            }
            #pragma unroll
            for (int o = 8; o >= 1; o >>= 1) den += __shfl_xor(den, o, 16);
            float rd = 1.f / den;
            #pragma unroll
            for (int q = 0; q < 4; ++q) {
                int sdx = t + q * 16;
                if (sdx < 63) alpha[d * 64 + sdx] = e_[q] * rd;
            }
        }
    }
    __syncthreads();

    for (int idx = tid; idx < 63 * FIN; idx += 768) {
        int d = idx / FIN, f = idx - d * FIN;
        float v = 0.f;
        for (int sdx = 0; sdx < 63; ++sdx)
            v += alpha[d * 64 + sdx] * hs[sdx * 252 + f];
        out[idx] = v;
    }
}

extern "C" void kernel_launch(void* const* d_in, const int* in_sizes, int n_in,
                              void* d_out, int out_size, void* d_ws, size_t ws_size,
                              hipStream_t stream) {
    (void)in_sizes; (void)n_in; (void)ws_size; (void)out_size;
    const float* x        = (const float*)d_in[0];
    const float* W        = (const float*)d_in[1];
    const float* att_src  = (const float*)d_in[2];
    const float* att_dst  = (const float*)d_in[3];
    const float* bias     = (const float*)d_in[4];
    float* out            = (float*)d_out;
    unsigned* cnt         = (unsigned*)d_ws;                       // 4 B
    unsigned* Wt          = (unsigned*)((char*)d_ws + 256);        // 128 KiB image

    hipMemsetAsync(cnt, 0, 4, stream);
    wt_prep<<<128, 256, 0, stream>>>(W, Wt);
    gat_gemm<<<NBLOCKS, 768, 0, stream>>>(x, Wt, bias, att_src, att_dst, cnt, out);
}

// Round 9
// 136.214 us; speedup vs baseline: 1.7303x; 1.5301x over previous
//
#include <hip/hip_runtime.h>
#include <hip/hip_bf16.h>

// Problem constants
#define FIN 250
#define NROWS 129024               // 2048*63
#define NTILES 8064                // 16-row tiles
#define NBLOCKS 252                // 32 tiles per block, exact
#define TILES_PER_BLOCK 32
#define PITCH 1040                 // x-row pitch in LDS (16B aligned; 2-way banks max)
#define WT_BYTES 128000            // 250 rows x 512 B
#define XB0 128000
#define XB1 (128000 + 16 * PITCH)  // 144640; end = 161280 <= 163840

typedef short short8 __attribute__((ext_vector_type(8)));
typedef float f32x4 __attribute__((ext_vector_type(4)));

__device__ __forceinline__ short f2bf(float f) {
    __bf16 b = (__bf16)f;
    return __builtin_bit_cast(short, b);
}

#define WAITV(n) asm volatile("s_waitcnt vmcnt(" #n ")" ::: "memory")
#define WAITL    asm volatile("s_waitcnt lgkmcnt(0)" ::: "memory")
#define HWBAR do { asm volatile("" ::: "memory"); __builtin_amdgcn_s_barrier(); \
                   asm volatile("" ::: "memory"); } while (0)

// Stage one 16-row x tile into LDS buffer (rows at PITCH). Wave wv stages rows
// 2wv, 2wv+1 -> exactly 2 vmcnt ops per wave. 1 KB contiguous per instruction.
__device__ __forceinline__ void stage_tile(const float* __restrict__ x,
                                           const float* __restrict__ xlast,
                                           char* lbuf, int tile, int wv, int lane) {
    #pragma unroll
    for (int i = 0; i < 2; ++i) {
        int r = wv * 2 + i;
        int grow = tile * 16 + r;
        const char* g = (grow == NROWS - 1) ? (const char*)xlast
                                            : (const char*)x + (size_t)grow * 1000u;
        g += lane * 16;
        char* l = lbuf + r * PITCH;
        __builtin_amdgcn_global_load_lds(
            (const __attribute__((address_space(1))) void*)g,
            (__attribute__((address_space(3))) void*)l, 16, 0, 0);
    }
}

// Pre-kernel: W^T bf16 image [c(250)][k(256 padded, k-pairs packed)] swizzled,
// plus zero-padded copy of the last x row (1024 B).
__global__ void __launch_bounds__(256)
wt_prep(const float* __restrict__ W, const float* __restrict__ x,
        unsigned* __restrict__ Wt, float* __restrict__ xlast) {
    int i = blockIdx.x * 256 + threadIdx.x;     // 125 blocks x 256 = 32000 words
    unsigned c  = (unsigned)i >> 7;             // 0..249
    unsigned kp = (unsigned)i & 127u;           // 0..127
    unsigned k0 = 2u * kp;
    unsigned lo = (k0 < FIN)      ? (unsigned)(unsigned short)f2bf(W[k0 * FIN + c]) : 0u;
    unsigned hi = (k0 + 1u < FIN) ? (unsigned)(unsigned short)f2bf(W[(k0 + 1u) * FIN + c]) : 0u;
    unsigned off = (c << 9) + ((4u * kp) ^ ((c & 7u) << 4));
    *(unsigned*)((char*)Wt + off) = lo | (hi << 16);
    if (blockIdx.x == 0) {
        int t = threadIdx.x;                    // 256 floats = 1024 B
        xlast[t] = (t < FIN) ? x[(size_t)(NROWS - 1) * FIN + t] : 0.f;
    }
}

__global__ void __launch_bounds__(512, 1)
gat_gemm(const float* __restrict__ x, const unsigned* __restrict__ Wt,
         const float* __restrict__ xlast, const float* __restrict__ bias,
         float* __restrict__ out)
{
    __shared__ __align__(16) char lds[161280];

    const int tid  = threadIdx.x;
    const int lane = tid & 63;
    const int wv   = tid >> 6;        // 0..7: owns cols wv*32 .. wv*32+31
    const int m    = lane & 15;
    const int kg   = lane >> 4;

    // Stage prebuilt W^T image (L2-hot): dumb vector copy.
    {
        const uint4* s4 = (const uint4*)Wt;
        uint4* d4 = (uint4*)lds;
        for (int i = tid; i < WT_BYTES / 16; i += 512) d4[i] = s4[i];
    }
    __syncthreads();                  // drains vmcnt+lgkm: clean slate

    const unsigned bswz = ((unsigned)(m & 7)) << 4;
    const int c0 = wv * 32 + m;       // <= 239, always valid
    const int c1 = c0 + 16;           // may be >= 250 for wv==7, m>=10
    const float bc0 = bias[c0];
    const float bc1 = (c1 < FIN) ? bias[c1] : 0.f;
    const char* wt = lds;
    const char* arow0 = lds + XB0 + m * PITCH;
    const char* arow1 = lds + XB1 + m * PITCH;

    const int t0 = blockIdx.x * TILES_PER_BLOCK;

    stage_tile(x, xlast, lds + XB0, t0, wv, lane);

    #pragma unroll 1
    for (int i = 0; i < TILES_PER_BLOCK; ++i) {
        const int t = t0 + i;
        if (i < TILES_PER_BLOCK - 1) {
            stage_tile(x, xlast, lds + (((i + 1) & 1) ? XB1 : XB0), t + 1, wv, lane);
            WAITV(2);                 // drain stage(t); keep stage(t+1) in flight
        } else {
            WAITV(0);
        }
        HWBAR;                        // all waves' stage(t) landed

        f32x4 acc0 = {bc0, bc0, bc0, bc0};
        f32x4 acc1 = {bc1, bc1, bc1, bc1};
        const char* ar = (i & 1) ? arow1 : arow0;
        const unsigned abase = (unsigned)(kg * 32);
        #pragma unroll
        for (int kk = 0; kk < 8; ++kk) {
            float4 a0 = *(const float4*)(ar + abase + kk * 128);
            float4 a1 = *(const float4*)(ar + abase + kk * 128 + 16);
            short8 af;
            af[0] = f2bf(a0.x); af[1] = f2bf(a0.y); af[2] = f2bf(a0.z); af[3] = f2bf(a0.w);
            af[4] = f2bf(a1.x); af[5] = f2bf(a1.y); af[6] = f2bf(a1.z); af[7] = f2bf(a1.w);
            unsigned koff = ((unsigned)(kk * 64 + kg * 16)) ^ bswz;
            short8 b0 = *(const short8*)(wt + ((unsigned)c0 << 9) + koff);
            short8 b1 = *(const short8*)(wt + ((unsigned)c1 << 9) + koff);
            acc0 = __builtin_amdgcn_mfma_f32_16x16x32_bf16(af, b0, acc0, 0, 0, 0);
            acc1 = __builtin_amdgcn_mfma_f32_16x16x32_bf16(af, b1, acc1, 0, 0, 0);
        }
        WAITL;                        // all my ds_reads of buf(t) complete
        HWBAR;                        // safe to overwrite buf(t) next iteration

        // C/D layout: col = lane&15 (=m), row = kg*4 + j
        unsigned obase = ((unsigned)t * 16 + (unsigned)kg * 4) * FIN + (unsigned)(wv * 32 + m);
        #pragma unroll
        for (int j = 0; j < 4; ++j) out[obase + (unsigned)(j * FIN)] = acc0[j];
        if (wv < 7 || m < 10) {       // mask cols 250..255
            #pragma unroll
            for (int j = 0; j < 4; ++j) out[obase + 16u + (unsigned)(j * FIN)] = acc1[j];
        }
    }
}

// 63-node GAT attention over rows 0..62 of out (holding h+bias). Exact: uniform
// logit shifts cancel in softmax and sum(alpha)=1 folds the bias through the mix.
__global__ void __launch_bounds__(1024, 1)
gat_attn(const float* __restrict__ att_src, const float* __restrict__ att_dst,
         float* __restrict__ out)
{
    __shared__ float hs[63 * 252];
    __shared__ float asrc[64], adst[64];
    __shared__ float alpha[63 * 64];

    const int tid = threadIdx.x;

    for (int idx = tid; idx < 63 * FIN; idx += 1024) {
        int r = idx / FIN, f = idx - r * FIN;
        hs[r * 252 + f] = out[idx];
    }
    __syncthreads();

    {   // logits: 16 threads per row, shfl-reduce
        int r = tid >> 4, t = tid & 15;
        float s1 = 0.f, s2 = 0.f;
        if (r < 63) {
            for (int k = t; k < FIN; k += 16) {
                float h = hs[r * 252 + k];
                s1 += h * att_src[k];
                s2 += h * att_dst[k];
            }
        }
        #pragma unroll
        for (int o = 8; o >= 1; o >>= 1) {
            s1 += __shfl_xor(s1, o, 16);
            s2 += __shfl_xor(s2, o, 16);
        }
        if (r < 63 && t == 0) { asrc[r] = s1; adst[r] = s2; }
    }
    __syncthreads();

    {   // softmax per dst row: 16 threads per row
        int d = tid >> 4, t = tid & 15;
        if (d < 63) {
            float ad = adst[d];
            float e_[4];
            float mx = -1e30f;
            #pragma unroll
            for (int q = 0; q < 4; ++q) {
                int sdx = t + q * 16;
                float e = -1e30f;
                if (sdx < 63) {
                    e = asrc[sdx] + ad;
                    e = e > 0.f ? e : 0.2f * e;     // leaky_relu slope 0.2
                }
                e_[q] = e;
                mx = fmaxf(mx, e);
            }
            #pragma unroll
            for (int o = 8; o >= 1; o >>= 1) mx = fmaxf(mx, __shfl_xor(mx, o, 16));
            float den = 0.f;
            #pragma unroll
            for (int q = 0; q < 4; ++q) {
                int sdx = t + q * 16;
                float ex = (sdx < 63) ? __expf(e_[q] - mx) : 0.f;
                e_[q] = ex;
                den += ex;
            }
            #pragma unroll
            for (int o = 8; o >= 1; o >>= 1) den += __shfl_xor(den, o, 16);
            float rd = 1.f / den;
            #pragma unroll
            for (int q = 0; q < 4; ++q) {
                int sdx = t + q * 16;
                if (sdx < 63) alpha[d * 64 + sdx] = e_[q] * rd;
            }
        }
    }
    __syncthreads();

    for (int idx = tid; idx < 63 * FIN; idx += 1024) {
        int d = idx / FIN, f = idx - d * FIN;
        float v = 0.f;
        for (int sdx = 0; sdx < 63; ++sdx)
            v += alpha[d * 64 + sdx] * hs[sdx * 252 + f];
        out[idx] = v;
    }
}

extern "C" void kernel_launch(void* const* d_in, const int* in_sizes, int n_in,
                              void* d_out, int out_size, void* d_ws, size_t ws_size,
                              hipStream_t stream) {
    (void)in_sizes; (void)n_in; (void)ws_size; (void)out_size;
    const float* x        = (const float*)d_in[0];
    const float* W        = (const float*)d_in[1];
    const float* att_src  = (const float*)d_in[2];
    const float* att_dst  = (const float*)d_in[3];
    const float* bias     = (const float*)d_in[4];
    float* out            = (float*)d_out;
    unsigned* Wt          = (unsigned*)d_ws;                       // 128 KiB image
    float* xlast          = (float*)((char*)d_ws + 131072);        // 1 KiB padded row

    wt_prep<<<125, 256, 0, stream>>>(W, x, Wt, xlast);
    gat_gemm<<<NBLOCKS, 512, 0, stream>>>(x, Wt, xlast, bias, out);
    gat_attn<<<1, 1024, 0, stream>>>(att_src, att_dst, out);
}

// Round 10
// 86.780 us; speedup vs baseline: 2.7160x; 1.5697x over previous
//
#include <hip/hip_runtime.h>
#include <hip/hip_bf16.h>

// Problem constants
#define FIN 250
#define NROWS 129024               // 2048*63
#define NT 16                      // tiles per block
#define NBLK 504                   // 504*16 = 8064 16-row tiles, exact

typedef short short8 __attribute__((ext_vector_type(8)));
typedef float f32x4 __attribute__((ext_vector_type(4)));

__device__ __forceinline__ short f2bf(float f) {
    __bf16 b = (__bf16)f;
    return __builtin_bit_cast(short, b);
}

#define WAITV(n) asm volatile("s_waitcnt vmcnt(" #n ")" ::: "memory")
#define WAITL    asm volatile("s_waitcnt lgkmcnt(0)" ::: "memory")
#define HWBAR do { asm volatile("" ::: "memory"); __builtin_amdgcn_s_barrier(); \
                   asm volatile("" ::: "memory"); } while (0)

// Stage one 16-row fp32 x-tile (pitch 1024B, linear) via global_load_lds w16.
// Wave wv stages rows wv*4..wv*4+3 -> exactly 4 vmcnt ops per wave.
__device__ __forceinline__ void stage_tile(const float* __restrict__ x,
                                           const float* __restrict__ xlast,
                                           char* lbuf, int tile, int wv, int lane) {
    #pragma unroll
    for (int i = 0; i < 4; ++i) {
        int r = wv * 4 + i;
        int grow = tile * 16 + r;
        const char* g = (grow == NROWS - 1) ? (const char*)xlast
                                            : (const char*)x + (size_t)grow * 1000u;
        g += lane * 16;
        char* l = lbuf + r * 1024;
        __builtin_amdgcn_global_load_lds(
            (const __attribute__((address_space(1))) void*)g,
            (__attribute__((address_space(3))) void*)l, 16, 0, 0);
    }
}

// Pre-kernel: W^T bf16 image, LINEAR [c(256)][k(256 padded, k-pairs packed)],
// zero-padded rows/cols; plus zero-padded copy of the last x row.
__global__ void __launch_bounds__(256)
wt_prep(const float* __restrict__ W, const float* __restrict__ x,
        unsigned* __restrict__ Wt, float* __restrict__ xlast) {
    int i = blockIdx.x * 256 + threadIdx.x;     // 128 blocks x 256 = 32768 words
    unsigned c  = (unsigned)i >> 7;             // 0..255
    unsigned kp = (unsigned)i & 127u;           // 0..127
    unsigned k0 = 2u * kp;
    unsigned lo = 0u, hi = 0u;
    if (c < FIN) {
        if (k0 < FIN)      lo = (unsigned)(unsigned short)f2bf(W[k0 * FIN + c]);
        if (k0 + 1u < FIN) hi = (unsigned)(unsigned short)f2bf(W[(k0 + 1u) * FIN + c]);
    }
    Wt[(c << 7) + kp] = lo | (hi << 16);
    if (blockIdx.x == 0) {
        int t = threadIdx.x;                    // 256 floats = 1024 B
        xlast[t] = (t < FIN) ? x[(size_t)(NROWS - 1) * FIN + t] : 0.f;
    }
}

// 256-thread blocks (the ONLY proven high-VGPR regime), W-frags in registers,
// A repacked to conflict-free bf16 fragment layout in LDS.
__global__ void __launch_bounds__(256, 1)
gat_gemm(const float* __restrict__ x, const unsigned short* __restrict__ Wt,
         const float* __restrict__ xlast, const float* __restrict__ bias,
         float* __restrict__ out)
{
    // [0,32768): fp32 stage double-buffer (2 x 16 rows x 1024B)
    // [32768,40960): bf16 afrag buffer: afrag[kk][slot]*16B, slot = lane^kk
    __shared__ __align__(16) char lds[40960];

    const int tid  = threadIdx.x;
    const int lane = tid & 63;
    const int wv   = tid >> 6;        // 0..3: owns cols wv*64 .. wv*64+63
    const int m    = lane & 15;
    const int kg   = lane >> 4;

    // ---- B-fragments in registers for the whole kernel (loaded once, L2/L3-hot) ----
    short8 b[4][8];
    #pragma unroll
    for (int f = 0; f < 4; ++f)
        #pragma unroll
        for (int kk = 0; kk < 8; ++kk)
            b[f][kk] = *(const short8*)((const char*)Wt
                         + ((size_t)(wv * 64 + f * 16 + m) << 9) + kk * 64 + kg * 16);

    float bc[4];
    #pragma unroll
    for (int f = 0; f < 4; ++f) {
        int c = wv * 64 + f * 16 + m;
        bc[f] = (c < FIN) ? bias[c] : 0.f;
    }

    char* const afr = lds + 32768;
    // repack writer decomposition: lane holds k = 4*lane .. 4*lane+3
    const int wkk   = lane >> 3;          // frag kk
    const int wkg   = (lane >> 1) & 3;    // frag kg
    const int whalf = lane & 1;           // frag half (j 0-3 vs 4-7)

    const int t0 = blockIdx.x * NT;
    stage_tile(x, xlast, lds, t0, wv, lane);

    #pragma unroll 1
    for (int i = 0; i < NT; ++i) {
        const int t = t0 + i;
        // Issue next stage, then drain current (counted: 16 stores + 4 stages newer).
        if (i + 1 < NT) {
            stage_tile(x, xlast, lds + ((i + 1) & 1) * 16384, t + 1, wv, lane);
            if (i == 0) { WAITV(4); } else { WAITV(20); }
        } else {
            WAITV(16);
        }
        HWBAR;                          // stage(t) visible; afrag(t-1) fully consumed

        // ---- repack: rows wv*4..wv*4+3, fp32 row-linear read -> bf16 frag write ----
        {
            const char* sb = lds + (i & 1) * 16384;
            #pragma unroll
            for (int rr = 0; rr < 4; ++rr) {
                int row = wv * 4 + rr;
                float4 v = *(const float4*)(sb + row * 1024 + lane * 16);
                unsigned lo = (unsigned)(unsigned short)f2bf(v.x)
                            | ((unsigned)(unsigned short)f2bf(v.y) << 16);
                unsigned hi = (unsigned)(unsigned short)f2bf(v.z)
                            | ((unsigned)(unsigned short)f2bf(v.w) << 16);
                uint2 pk = make_uint2(lo, hi);
                *(uint2*)(afr + wkk * 1024 + wkg * 256 + ((row ^ wkk) * 16) + whalf * 8) = pk;
            }
        }
        WAITL;
        HWBAR;                          // afrag(t) ready for all waves

        // ---- compute: 8 kk x 4 col-frags; A-read = 1 conflict-free b128 per kk ----
        f32x4 acc[4];
        #pragma unroll
        for (int f = 0; f < 4; ++f) acc[f] = (f32x4){bc[f], bc[f], bc[f], bc[f]};
        #pragma unroll
        for (int kk = 0; kk < 8; ++kk) {
            short8 af = *(const short8*)(afr + kk * 1024 + kg * 256 + ((m ^ kk) * 16));
            #pragma unroll
            for (int f = 0; f < 4; ++f)
                acc[f] = __builtin_amdgcn_mfma_f32_16x16x32_bf16(af, b[f][kk], acc[f], 0, 0, 0);
        }

        // ---- stores: 16 global_store_dword per wave (uniform count for vmcnt math) ----
        // C/D layout: col = lane&15 (=m), row = kg*4 + j
        unsigned obase = ((unsigned)t * 16 + (unsigned)kg * 4) * FIN + (unsigned)(wv * 64 + m);
        #pragma unroll
        for (int f = 0; f < 4; ++f) {
            bool ok = (wv < 3) || (f < 3) || (m < 10);   // mask cols 250..255
            if (ok) {
                #pragma unroll
                for (int j = 0; j < 4; ++j)
                    out[obase + (unsigned)(f * 16) + (unsigned)(j * FIN)] = acc[f][j];
            }
        }
    }
}

// 63-node GAT attention over rows 0..62 of out (holding h+bias). Exact: uniform
// logit shifts cancel in softmax and sum(alpha)=1 folds the bias through the mix.
__global__ void __launch_bounds__(1024, 1)
gat_attn(const float* __restrict__ att_src, const float* __restrict__ att_dst,
         float* __restrict__ out)
{
    __shared__ float hs[63 * 252];
    __shared__ float asrc[64], adst[64];
    __shared__ float alpha[63 * 64];

    const int tid = threadIdx.x;

    for (int idx = tid; idx < 63 * FIN; idx += 1024) {
        int r = idx / FIN, f = idx - r * FIN;
        hs[r * 252 + f] = out[idx];
    }
    __syncthreads();

    {   // logits: 16 threads per row, shfl-reduce
        int r = tid >> 4, t = tid & 15;
        float s1 = 0.f, s2 = 0.f;
        if (r < 63) {
            for (int k = t; k < FIN; k += 16) {
                float h = hs[r * 252 + k];
                s1 += h * att_src[k];
                s2 += h * att_dst[k];
            }
        }
        #pragma unroll
        for (int o = 8; o >= 1; o >>= 1) {
            s1 += __shfl_xor(s1, o, 16);
            s2 += __shfl_xor(s2, o, 16);
        }
        if (r < 63 && t == 0) { asrc[r] = s1; adst[r] = s2; }
    }
    __syncthreads();

    {   // softmax per dst row: 16 threads per row
        int d = tid >> 4, t = tid & 15;
        if (d < 63) {
            float ad = adst[d];
            float e_[4];
            float mx = -1e30f;
            #pragma unroll
            for (int q = 0; q < 4; ++q) {
                int sdx = t + q * 16;
                float e = -1e30f;
                if (sdx < 63) {
                    e = asrc[sdx] + ad;
                    e = e > 0.f ? e : 0.2f * e;     // leaky_relu slope 0.2
                }
                e_[q] = e;
                mx = fmaxf(mx, e);
            }
            #pragma unroll
            for (int o = 8; o >= 1; o >>= 1) mx = fmaxf(mx, __shfl_xor(mx, o, 16));
            float den = 0.f;
            #pragma unroll
            for (int q = 0; q < 4; ++q) {
                int sdx = t + q * 16;
                float ex = (sdx < 63) ? __expf(e_[q] - mx) : 0.f;
                e_[q] = ex;
                den += ex;
            }
            #pragma unroll
            for (int o = 8; o >= 1; o >>= 1) den += __shfl_xor(den, o, 16);
            float rd = 1.f / den;
            #pragma unroll
            for (int q = 0; q < 4; ++q) {
                int sdx = t + q * 16;
                if (sdx < 63) alpha[d * 64 + sdx] = e_[q] * rd;
            }
        }
    }
    __syncthreads();

    for (int idx = tid; idx < 63 * FIN; idx += 1024) {
        int d = idx / FIN, f = idx - d * FIN;
        float v = 0.f;
        for (int sdx = 0; sdx < 63; ++sdx)
            v += alpha[d * 64 + sdx] * hs[sdx * 252 + f];
        out[idx] = v;
    }
}

extern "C" void kernel_launch(void* const* d_in, const int* in_sizes, int n_in,
                              void* d_out, int out_size, void* d_ws, size_t ws_size,
                              hipStream_t stream) {
    (void)in_sizes; (void)n_in; (void)ws_size; (void)out_size;
    const float* x        = (const float*)d_in[0];
    const float* W        = (const float*)d_in[1];
    const float* att_src  = (const float*)d_in[2];
    const float* att_dst  = (const float*)d_in[3];
    const float* bias     = (const float*)d_in[4];
    float* out            = (float*)d_out;
    unsigned* Wt          = (unsigned*)d_ws;                       // 128 KiB image
    float* xlast          = (float*)((char*)d_ws + 131072);        // 1 KiB padded row

    wt_prep<<<128, 256, 0, stream>>>(W, x, Wt, xlast);
    gat_gemm<<<NBLK, 256, 0, stream>>>(x, (const unsigned short*)Wt, xlast, bias, out);
    gat_attn<<<1, 1024, 0, stream>>>(att_src, att_dst, out);
}